// Round 7
// baseline (79.243 us; speedup 1.0000x reference)
//
#include <hip/hip_runtime.h>
#include <hip/hip_cooperative_groups.h>

namespace cg = cooperative_groups;

#define EMBED 512
#define NTOK 8192
#define MT 16            // tokens per block (one MFMA M-tile)
#define NB1 6            // GEMM1 N-fragments (96 cols = 16 h | 64 G | 4 xb | pad)
#define KS1 16           // GEMM1 K-steps (512/32)
#define NB2 32           // GEMM2 N-fragments (512 cols)
#define KS2 3            // GEMM2 K-steps (96/32; rows 68..95 zero)
#define B1ELEMS (KS1 * NB1 * 64 * 8)   // 49152
#define B2ELEMS (KS2 * NB2 * 64 * 8)   // 49152
#define XR 520           // LDS x row pitch (halves): 1040 B == 4 banks mod 32
#define ZR 104           // LDS z row pitch (halves): 208 B == 20 banks mod 32

using half8   = __attribute__((ext_vector_type(8))) _Float16;
using half2_t = __attribute__((ext_vector_type(2))) _Float16;
using f32x4   = __attribute__((ext_vector_type(4))) float;

#define MFMA16(a, b, c) __builtin_amdgcn_mfma_f32_16x16x32_f16((a), (b), (c), 0, 0, 0)

__device__ __forceinline__ half2_t pkrtz(float a, float b) {
    return __builtin_bit_cast(half2_t, __builtin_amdgcn_cvt_pkrtz(a, b));
}

// ---------------------------------------------------------------------------
// Single cooperative kernel:
//   phase A: issue x loads to regs; pack one B-frag element per thread
//   grid.sync()
//   phase B: x->f16 LDS; GEMM1 -> glue -> GEMM2 (R5 structure, 512 blocks)
// B-frag order: frag(kstep,nf): lane l holds B[k=kstep*32+(l>>4)*8+i][col=nf*16+(l&15)]
// ---------------------------------------------------------------------------
__global__ __launch_bounds__(256, 2) void fused(const float* __restrict__ x,
                                                const float* __restrict__ fc1w,
                                                const float* __restrict__ fc1b,
                                                const float* __restrict__ fc2w,
                                                const float* __restrict__ fc2b,
                                                _Float16* __restrict__ b1f,
                                                _Float16* __restrict__ b2f,
                                                float* __restrict__ out)
{
    __shared__ _Float16 xh[MT][XR];         // 16.6 KB f16 x-tile
    __shared__ float    c1s[MT][100];       // 6.4 KB GEMM1 result spill
    __shared__ _Float16 zh[MT][ZR];         // 3.3 KB Z (f16)

    const int tid  = threadIdx.x;
    const int lane = tid & 63;
    const int wv   = tid >> 6;
    const int rowA = lane & 15;             // token row inside tile
    const int kgrp = lane >> 4;             // 0..3
    const long tok0 = (long)blockIdx.x * MT;

    // ---- phase A.1: issue this block's x-tile loads into registers ----------
    float4 xr[8];
    {
        const float4* xg = reinterpret_cast<const float4*>(x + tok0 * EMBED);
        #pragma unroll
        for (int i = 0; i < 8; ++i) xr[i] = xg[tid + i * 256];
    }

    // ---- phase A.2: pack one b1f / b2f element (98304 over 131072 threads) --
    {
        const int g = blockIdx.x * 256 + tid;
        if (g < B1ELEMS) {
            // B1: cols 0-15 fc1w^T | 16-79 W1[e][j][k] | 80-83 b1[e][j] | 84+ 0
            const int elem = g & 7, ln = (g >> 3) & 63, rest = g >> 9;
            const int nf = rest % NB1, kstep = rest / NB1;
            const int krow = kstep * 32 + (ln >> 4) * 8 + elem;       // e
            const int c = nf * 16 + (ln & 15);
            float v;
            if (c < 16)      v = fc1w[c * EMBED + krow];
            else if (c < 80) { int cc = c - 16; v = fc2w[(krow * 4 + (cc >> 4)) * 16 + (cc & 15)]; }
            else if (c < 84) v = fc2b[krow * 4 + (c - 80)];
            else             v = 0.f;
            b1f[g] = (_Float16)v;
        } else if (g < 2 * B1ELEMS) {
            // B2: rows j*16+k -> W2[j][e][k]; rows 64+j -> b2[j][e]; rows 68+ 0
            const int i2 = g - B1ELEMS;
            const int elem = i2 & 7, ln = (i2 >> 3) & 63, rest = i2 >> 9;
            const int nf = rest & 31, kstep = rest >> 5;
            const int krow = kstep * 32 + (ln >> 4) * 8 + elem;       // 0..95
            const int e = nf * 16 + (ln & 15);
            float v;
            if (krow < 64)      v = fc2w[(2048 + (krow >> 4) * 512 + e) * 16 + (krow & 15)];
            else if (krow < 68) v = fc2b[2048 + (krow - 64) * 512 + e];
            else                v = 0.f;
            b2f[i2] = (_Float16)v;
        }
    }

    cg::this_grid().sync();

    // ---- phase B.0: x regs -> f16 LDS ---------------------------------------
    {
        #pragma unroll
        for (int i = 0; i < 8; ++i) {
            const int idx = tid + i * 256;            // 2048 float4
            const int t = idx >> 7, e4 = idx & 127;
            half2_t p0 = pkrtz(xr[i].x, xr[i].y), p1 = pkrtz(xr[i].z, xr[i].w);
            uint2 w;
            w.x = __builtin_bit_cast(unsigned, p0);
            w.y = __builtin_bit_cast(unsigned, p1);
            *reinterpret_cast<uint2*>(&xh[t][e4 * 4]) = w;
        }
    }
    __syncthreads();

    // ================= GEMM1: X[16x512] * B1[512x96] =========================
    f32x4 accA = {0.f, 0.f, 0.f, 0.f};
    f32x4 accB = {0.f, 0.f, 0.f, 0.f};
    const int nfA = wv;
    const int nfB = 4 + wv;
    const bool hasB = (wv < 2);

    #pragma unroll
    for (int ks = 0; ks < KS1; ++ks) {
        half8 a = *reinterpret_cast<const half8*>(&xh[rowA][ks * 32 + kgrp * 8]);
        half8 bA = *reinterpret_cast<const half8*>(b1f + ((ks * NB1 + nfA) * 64 + lane) * 8);
        accA = MFMA16(a, bA, accA);
        if (hasB) {
            half8 bB = *reinterpret_cast<const half8*>(b1f + ((ks * NB1 + nfB) * 64 + lane) * 8);
            accB = MFMA16(a, bB, accB);
        }
    }
    #pragma unroll
    for (int r = 0; r < 4; ++r) c1s[kgrp * 4 + r][nfA * 16 + rowA] = accA[r];
    if (hasB) {
        #pragma unroll
        for (int r = 0; r < 4; ++r) c1s[kgrp * 4 + r][nfB * 16 + rowA] = accB[r];
    }
    __syncthreads();

    // ================= glue: h, y1, Z = (y1 (x) h | y1 | 0) ==================
    if (tid < 64) {
        const int t = tid & 15, j = tid >> 4;
        float h[16];
        #pragma unroll
        for (int k = 0; k < 16; ++k) h[k] = fmaxf(c1s[t][k] + fc1b[k], 0.f);
        float y1 = c1s[t][80 + j];
        #pragma unroll
        for (int k = 0; k < 16; ++k) y1 = fmaf(c1s[t][16 + j * 16 + k], h[k], y1);
        y1 = fmaxf(y1, 0.f);
        #pragma unroll
        for (int k = 0; k < 16; k += 2) {
            half2_t p = pkrtz(y1 * h[k], y1 * h[k + 1]);
            *reinterpret_cast<half2_t*>(&zh[t][j * 16 + k]) = p;
        }
        zh[t][64 + j] = (_Float16)y1;
        #pragma unroll
        for (int p = 0; p < 7; ++p) zh[t][68 + j * 7 + p] = (_Float16)0.f;
    }
    __syncthreads();

    // ================= GEMM2: Z[16x96] * B2[96x512] ==========================
    f32x4 acc2[8];
    #pragma unroll
    for (int f = 0; f < 8; ++f) acc2[f] = (f32x4){0.f, 0.f, 0.f, 0.f};

    #pragma unroll
    for (int ks = 0; ks < KS2; ++ks) {
        half8 az = *reinterpret_cast<const half8*>(&zh[rowA][ks * 32 + kgrp * 8]);
        #pragma unroll
        for (int f = 0; f < 8; ++f) {
            half8 bv = *reinterpret_cast<const half8*>(b2f + ((ks * NB2 + wv * 8 + f) * 64 + lane) * 8);
            acc2[f] = MFMA16(az, bv, acc2[f]);
        }
    }

    // ================= relu + store ==========================================
    #pragma unroll
    for (int f = 0; f < 8; ++f) {
        const int e = (wv * 8 + f) * 16 + rowA;
        #pragma unroll
        for (int r = 0; r < 4; ++r) {
            out[(tok0 + kgrp * 4 + r) * EMBED + e] = fmaxf(acc2[f][r], 0.f);
        }
    }
}

extern "C" void kernel_launch(void* const* d_in, const int* in_sizes, int n_in,
                              void* d_out, int out_size, void* d_ws, size_t ws_size,
                              hipStream_t stream) {
    const float* x    = (const float*)d_in[0];
    const float* fc1w = (const float*)d_in[1];
    const float* fc1b = (const float*)d_in[2];
    const float* fc2w = (const float*)d_in[3];
    const float* fc2b = (const float*)d_in[4];
    float* out = (float*)d_out;

    _Float16* b1f = (_Float16*)d_ws;                   // 96 KB
    _Float16* b2f = b1f + B1ELEMS;                     // 96 KB

    void* args[] = {(void*)&x, (void*)&fc1w, (void*)&fc1b, (void*)&fc2w,
                    (void*)&fc2b, (void*)&b1f, (void*)&b2f, (void*)&out};
    hipLaunchCooperativeKernel(reinterpret_cast<void*>(fused),
                               dim3(NTOK / MT), dim3(256), args, 0, stream);
}

// Round 8
// 19.125 us; speedup vs baseline: 4.1434x; 4.1434x over previous
//
#include <hip/hip_runtime.h>

#define EMBED 512
#define NTOK 8192
#define MT 16            // tokens per block (one MFMA M-tile)
#define NB1 6            // GEMM1 N-fragments (96 cols = 16 h | 64 G | 4 xb | pad)
#define KS1 16           // GEMM1 K-steps (512/32)
#define NB2 32           // GEMM2 N-fragments (512 cols)
#define KS2 3            // GEMM2 K-steps (96/32; rows 68..95 zero)
#define B1ELEMS (KS1 * NB1 * 64 * 8)   // 49152
#define B2ELEMS (KS2 * NB2 * 64 * 8)   // 49152
#define XR 520           // LDS x row pitch (halves): 1040 B == 4 banks mod 32
#define ZR 104           // LDS z row pitch (halves): 208 B == 20 banks mod 32

using half8   = __attribute__((ext_vector_type(8))) _Float16;
using half2_t = __attribute__((ext_vector_type(2))) _Float16;
using f32x4   = __attribute__((ext_vector_type(4))) float;

#define MFMA16(a, b, c) __builtin_amdgcn_mfma_f32_16x16x32_f16((a), (b), (c), 0, 0, 0)

__device__ __forceinline__ half2_t pkrtz(float a, float b) {
    return __builtin_bit_cast(half2_t, __builtin_amdgcn_cvt_pkrtz(a, b));
}

// ---------------------------------------------------------------------------
// prep: pack B1 [512 x 96] and B2 [96 x 512] (f16, RNE) in MFMA B-frag order:
// frag(kstep, nf): lane l supplies B[k = kstep*32 + (l>>4)*8 + i][col = nf*16 + (l&15)]
// flat [kstep][nf][lane][i] -> coalesced 16B/lane in main.
// ---------------------------------------------------------------------------
__global__ __launch_bounds__(256) void prep(const float* __restrict__ fc1w,
                                            const float* __restrict__ fc2w,
                                            const float* __restrict__ fc2b,
                                            _Float16* __restrict__ b1f,
                                            _Float16* __restrict__ b2f)
{
    const int i = blockIdx.x * 256 + threadIdx.x;      // 0..49151
    // ---- B1: cols 0-15 fc1w^T | 16-79 W1[e][j][k] | 80-83 b1[e][j] | 84+ zero
    {
        const int elem = i & 7, lane = (i >> 3) & 63, rest = i >> 9;
        const int nf = rest % NB1, kstep = rest / NB1;
        const int krow = kstep * 32 + (lane >> 4) * 8 + elem;         // e
        const int c = nf * 16 + (lane & 15);
        float v;
        if (c < 16)      v = fc1w[c * EMBED + krow];
        else if (c < 80) { int cc = c - 16; v = fc2w[(krow * 4 + (cc >> 4)) * 16 + (cc & 15)]; }
        else if (c < 84) v = fc2b[krow * 4 + (c - 80)];
        else             v = 0.f;
        b1f[i] = (_Float16)v;
    }
    // ---- B2: rows j*16+k -> W2[j][e][k]; rows 64+j -> b2[j][e]; rows 68+ zero
    {
        const int elem = i & 7, lane = (i >> 3) & 63, rest = i >> 9;
        const int nf = rest & 31, kstep = rest >> 5;
        const int krow = kstep * 32 + (lane >> 4) * 8 + elem;         // 0..95
        const int e = nf * 16 + (lane & 15);
        float v;
        if (krow < 64)      v = fc2w[(2048 + (krow >> 4) * 512 + e) * 16 + (krow & 15)];
        else if (krow < 68) v = fc2b[2048 + (krow - 64) * 512 + e];
        else                v = 0.f;
        b2f[i] = (_Float16)v;
    }
}

// ---------------------------------------------------------------------------
// main: per block of 16 tokens. All B-fragments explicitly prefetched into
// registers so GEMM loops never expose L2 latency:
//   issue x loads + ALL B1 frag loads -> x->LDS -> GEMM1 (regs) ->
//   spill C1 + issue ALL B2 frag loads -> barrier -> glue -> barrier ->
//   GEMM2 (regs) -> store.
// ---------------------------------------------------------------------------
__global__ __launch_bounds__(256, 2) void hyper_main(const float* __restrict__ x,
                                                     const float* __restrict__ fc1b,
                                                     const _Float16* __restrict__ b1f,
                                                     const _Float16* __restrict__ b2f,
                                                     float* __restrict__ out)
{
    __shared__ _Float16 xh[MT][XR];         // 16.6 KB f16 x-tile
    __shared__ float    c1s[MT][100];       // 6.4 KB GEMM1 result spill
    __shared__ _Float16 zh[MT][ZR];         // 3.3 KB Z (f16)

    const int tid  = threadIdx.x;
    const int lane = tid & 63;
    const int wv   = tid >> 6;
    const int rowA = lane & 15;             // token row inside tile
    const int kgrp = lane >> 4;             // 0..3
    const long tok0 = (long)blockIdx.x * MT;

    const int  nfA  = wv;
    const bool hasB = (wv < 2);
    const int  nfB  = hasB ? (4 + wv) : wv; // stay in-bounds for waves 2,3

    // ---- issue x-tile loads (HBM) -------------------------------------------
    float4 xr[8];
    {
        const float4* xg = reinterpret_cast<const float4*>(x + tok0 * EMBED);
        #pragma unroll
        for (int i = 0; i < 8; ++i) xr[i] = xg[tid + i * 256];
    }

    // ---- B1 full register prefetch (overlaps x HBM latency) -----------------
    half8 b1a[KS1], b1b[KS1];
    #pragma unroll
    for (int ks = 0; ks < KS1; ++ks)
        b1a[ks] = *reinterpret_cast<const half8*>(b1f + ((ks * NB1 + nfA) * 64 + lane) * 8);
    #pragma unroll
    for (int ks = 0; ks < KS1; ++ks)
        b1b[ks] = *reinterpret_cast<const half8*>(b1f + ((ks * NB1 + nfB) * 64 + lane) * 8);

    // ---- x regs -> f16 LDS --------------------------------------------------
    {
        #pragma unroll
        for (int i = 0; i < 8; ++i) {
            const int idx = tid + i * 256;            // 2048 float4
            const int t = idx >> 7, e4 = idx & 127;
            half2_t p0 = pkrtz(xr[i].x, xr[i].y), p1 = pkrtz(xr[i].z, xr[i].w);
            uint2 w;
            w.x = __builtin_bit_cast(unsigned, p0);
            w.y = __builtin_bit_cast(unsigned, p1);
            *reinterpret_cast<uint2*>(&xh[t][e4 * 4]) = w;
        }
    }
    __syncthreads();

    // ================= GEMM1: X[16x512] * B1[512x96], B in regs ==============
    f32x4 accA = {0.f, 0.f, 0.f, 0.f};
    f32x4 accB = {0.f, 0.f, 0.f, 0.f};
    #pragma unroll
    for (int ks = 0; ks < KS1; ++ks) {
        half8 a = *reinterpret_cast<const half8*>(&xh[rowA][ks * 32 + kgrp * 8]);
        accA = MFMA16(a, b1a[ks], accA);
        if (hasB) accB = MFMA16(a, b1b[ks], accB);
    }
    #pragma unroll
    for (int r = 0; r < 4; ++r) c1s[kgrp * 4 + r][nfA * 16 + rowA] = accA[r];
    if (hasB) {
        #pragma unroll
        for (int r = 0; r < 4; ++r) c1s[kgrp * 4 + r][nfB * 16 + rowA] = accB[r];
    }

    // ---- issue B2 prefetch now: latency hides under glue + 2 barriers -------
    half8 b2r[KS2][8];
    #pragma unroll
    for (int ks = 0; ks < KS2; ++ks)
        #pragma unroll
        for (int f = 0; f < 8; ++f)
            b2r[ks][f] = *reinterpret_cast<const half8*>(
                b2f + ((ks * NB2 + wv * 8 + f) * 64 + lane) * 8);

    __syncthreads();

    // ================= glue: h, y1, Z = (y1 (x) h | y1 | 0) ==================
    if (tid < 64) {
        const int t = tid & 15, j = tid >> 4;
        float h[16];
        #pragma unroll
        for (int k = 0; k < 16; ++k) h[k] = fmaxf(c1s[t][k] + fc1b[k], 0.f);
        float y1 = c1s[t][80 + j];
        #pragma unroll
        for (int k = 0; k < 16; ++k) y1 = fmaf(c1s[t][16 + j * 16 + k], h[k], y1);
        y1 = fmaxf(y1, 0.f);
        #pragma unroll
        for (int k = 0; k < 16; k += 2) {
            half2_t p = pkrtz(y1 * h[k], y1 * h[k + 1]);
            *reinterpret_cast<half2_t*>(&zh[t][j * 16 + k]) = p;
        }
        zh[t][64 + j] = (_Float16)y1;
        #pragma unroll
        for (int p = 0; p < 7; ++p) zh[t][68 + j * 7 + p] = (_Float16)0.f;
    }
    __syncthreads();

    // ================= GEMM2: Z[16x96] * B2[96x512], B in regs ===============
    f32x4 acc2[8];
    #pragma unroll
    for (int f = 0; f < 8; ++f) acc2[f] = (f32x4){0.f, 0.f, 0.f, 0.f};

    #pragma unroll
    for (int ks = 0; ks < KS2; ++ks) {
        half8 az = *reinterpret_cast<const half8*>(&zh[rowA][ks * 32 + kgrp * 8]);
        #pragma unroll
        for (int f = 0; f < 8; ++f) acc2[f] = MFMA16(az, b2r[ks][f], acc2[f]);
    }

    // ================= relu + store ==========================================
    #pragma unroll
    for (int f = 0; f < 8; ++f) {
        const int e = (wv * 8 + f) * 16 + rowA;
        #pragma unroll
        for (int r = 0; r < 4; ++r) {
            out[(tok0 + kgrp * 4 + r) * EMBED + e] = fmaxf(acc2[f][r], 0.f);
        }
    }
}

extern "C" void kernel_launch(void* const* d_in, const int* in_sizes, int n_in,
                              void* d_out, int out_size, void* d_ws, size_t ws_size,
                              hipStream_t stream) {
    const float* x    = (const float*)d_in[0];
    const float* fc1w = (const float*)d_in[1];
    const float* fc1b = (const float*)d_in[2];
    const float* fc2w = (const float*)d_in[3];
    const float* fc2b = (const float*)d_in[4];
    float* out = (float*)d_out;

    _Float16* b1f = (_Float16*)d_ws;                   // 96 KB
    _Float16* b2f = b1f + B1ELEMS;                     // 96 KB

    prep<<<dim3(B1ELEMS / 256), dim3(256), 0, stream>>>(fc1w, fc2w, fc2b, b1f, b2f);
    hyper_main<<<dim3(NTOK / MT), dim3(256), 0, stream>>>(x, fc1b, b1f, b2f, out);
}

// Round 9
// 18.403 us; speedup vs baseline: 4.3059x; 1.0392x over previous
//
#include <hip/hip_runtime.h>

#define EMBED 512
#define NTOK 8192
#define MT 16            // tokens per block (one MFMA M-tile)
#define NB1 6            // GEMM1 N-fragments (96 cols = 16 h | 64 G | 4 xb | pad)
#define KS1 16           // GEMM1 K-steps (512/32)
#define NB2 32           // GEMM2 N-fragments (512 cols)
#define KS2 3            // GEMM2 K-steps (96/32; rows 68..95 zero)
#define B1ELEMS (KS1 * NB1 * 64 * 8)   // 49152
#define B2ELEMS (KS2 * NB2 * 64 * 8)   // 49152
#define XR 520           // LDS x row pitch (halves)
#define ZR 104           // LDS z row pitch (halves)

using half8   = __attribute__((ext_vector_type(8))) _Float16;
using half2_t = __attribute__((ext_vector_type(2))) _Float16;
using f32x4   = __attribute__((ext_vector_type(4))) float;

#define MFMA16(a, b, c) __builtin_amdgcn_mfma_f32_16x16x32_f16((a), (b), (c), 0, 0, 0)

__device__ __forceinline__ half2_t pkrtz(float a, float b) {
    return __builtin_bit_cast(half2_t, __builtin_amdgcn_cvt_pkrtz(a, b));
}

// ---------------------------------------------------------------------------
// prep (vectorized): each thread produces ONE half8 B-fragment slot (16B store).
// Slot order: frag(kstep,nf), lane l holds B[k=kstep*32+(l>>4)*8+i][col=nf*16+(l&15)]
// ---------------------------------------------------------------------------
__global__ __launch_bounds__(512) void prep(const float* __restrict__ fc1w,
                                            const float* __restrict__ fc2w,
                                            const float* __restrict__ fc2b,
                                            _Float16* __restrict__ b1f,
                                            _Float16* __restrict__ b2f)
{
    const int g = blockIdx.x * 512 + threadIdx.x;      // 0..12287 slots
    float v[8];
    if (g < B1ELEMS / 8) {
        // ---- B1 [512 x 96]: cols 0-15 fc1w^T | 16-79 W1 | 80-83 b1 | 84+ 0
        const int lane = g & 63, rest = g >> 6;
        const int nf = rest % NB1, kstep = rest / NB1;
        const int k0 = kstep * 32 + ((lane >> 4) << 3);   // e0
        const int c  = nf * 16 + (lane & 15);
        if (c < 16) {                                     // fc1w^T: contiguous
            const float4* p = reinterpret_cast<const float4*>(fc1w + c * EMBED + k0);
            float4 a = p[0], b = p[1];
            v[0]=a.x; v[1]=a.y; v[2]=a.z; v[3]=a.w; v[4]=b.x; v[5]=b.y; v[6]=b.z; v[7]=b.w;
        } else if (c < 80) {                              // W1: stride 64
            const int cc = c - 16;
            const float* p = fc2w + k0 * 64 + (cc >> 4) * 16 + (cc & 15);
            #pragma unroll
            for (int i = 0; i < 8; ++i) v[i] = p[i * 64];
        } else if (c < 84) {                              // b1: stride 4
            const float* p = fc2b + k0 * 4 + (c - 80);
            #pragma unroll
            for (int i = 0; i < 8; ++i) v[i] = p[i * 4];
        } else {
            #pragma unroll
            for (int i = 0; i < 8; ++i) v[i] = 0.f;
        }
        half8 h;
        #pragma unroll
        for (int i = 0; i < 8; ++i) h[i] = (_Float16)v[i];
        *reinterpret_cast<half8*>(b1f + g * 8) = h;
    } else if (g < (B1ELEMS + B2ELEMS) / 8) {
        // ---- B2 [96 x 512]: rows j*16+k -> W2[j][e][k]; 64+j -> b2[j][e]; 68+ 0
        const int g2 = g - B1ELEMS / 8;
        const int lane = g2 & 63, rest = g2 >> 6;
        const int nf = rest & 31, kstep = rest >> 5;
        const int k0 = kstep * 32 + ((lane >> 4) << 3);
        const int e  = nf * 16 + (lane & 15);
        if (k0 < 64) {                                    // W2: contiguous 8
            const float4* p = reinterpret_cast<const float4*>(
                fc2w + (2048 + (k0 >> 4) * 512 + e) * 16 + (k0 & 15));
            float4 a = p[0], b = p[1];
            v[0]=a.x; v[1]=a.y; v[2]=a.z; v[3]=a.w; v[4]=b.x; v[5]=b.y; v[6]=b.z; v[7]=b.w;
        } else if (k0 == 64) {                            // bias rows 64-67
            #pragma unroll
            for (int i = 0; i < 8; ++i)
                v[i] = (i < 4) ? fc2b[2048 + i * 512 + e] : 0.f;
        } else {
            #pragma unroll
            for (int i = 0; i < 8; ++i) v[i] = 0.f;
        }
        half8 h;
        #pragma unroll
        for (int i = 0; i < 8; ++i) h[i] = (_Float16)v[i];
        *reinterpret_cast<half8*>(b2f + g2 * 8) = h;
    }
}

// ---------------------------------------------------------------------------
// main: 512 threads (8 waves) per 16-token tile. B1: one frag per wave (0-5);
// GEMM2: 4 frags per wave. All B-frags register-prefetched; target <=128 VGPR
// so 2 blocks/CU co-reside (16 waves/CU).
// ---------------------------------------------------------------------------
__global__ __launch_bounds__(512, 4) void hyper_main(const float* __restrict__ x,
                                                     const float* __restrict__ fc1b,
                                                     const _Float16* __restrict__ b1f,
                                                     const _Float16* __restrict__ b2f,
                                                     float* __restrict__ out)
{
    __shared__ _Float16 xh[MT][XR];         // 16.6 KB f16 x-tile
    __shared__ float    c1s[MT][100];       // 6.4 KB GEMM1 result spill
    __shared__ _Float16 zh[MT][ZR];         // 3.3 KB Z (f16)

    const int tid  = threadIdx.x;
    const int lane = tid & 63;
    const int wv   = tid >> 6;              // 0..7
    const int rowA = lane & 15;
    const int kgrp = lane >> 4;             // 0..3
    const long tok0 = (long)blockIdx.x * MT;
    const bool hasG1 = (wv < 6);
    const int  nfA   = hasG1 ? wv : 0;

    // ---- issue x-tile loads (HBM): 2048 float4 / 512 threads ----------------
    float4 xr[4];
    {
        const float4* xg = reinterpret_cast<const float4*>(x + tok0 * EMBED);
        #pragma unroll
        for (int i = 0; i < 4; ++i) xr[i] = xg[tid + i * 512];
    }

    // ---- B1 register prefetch (one frag column per wave, overlaps x) --------
    half8 b1a[KS1];
    if (hasG1) {
        #pragma unroll
        for (int ks = 0; ks < KS1; ++ks)
            b1a[ks] = *reinterpret_cast<const half8*>(b1f + ((ks * NB1 + nfA) * 64 + lane) * 8);
    }

    // ---- x regs -> f16 LDS --------------------------------------------------
    {
        #pragma unroll
        for (int i = 0; i < 4; ++i) {
            const int idx = tid + i * 512;            // 2048 float4
            const int t = idx >> 7, e4 = idx & 127;
            half2_t p0 = pkrtz(xr[i].x, xr[i].y), p1 = pkrtz(xr[i].z, xr[i].w);
            uint2 w;
            w.x = __builtin_bit_cast(unsigned, p0);
            w.y = __builtin_bit_cast(unsigned, p1);
            *reinterpret_cast<uint2*>(&xh[t][e4 * 4]) = w;
        }
    }
    __syncthreads();

    // ================= GEMM1: X[16x512] * B1[512x96], waves 0-5 ==============
    f32x4 accA = {0.f, 0.f, 0.f, 0.f};
    if (hasG1) {
        #pragma unroll
        for (int ks = 0; ks < KS1; ++ks) {
            half8 a = *reinterpret_cast<const half8*>(&xh[rowA][ks * 32 + kgrp * 8]);
            accA = MFMA16(a, b1a[ks], accA);
        }
        #pragma unroll
        for (int r = 0; r < 4; ++r) c1s[kgrp * 4 + r][nfA * 16 + rowA] = accA[r];
    }

    // ---- B2 register prefetch: 4 frags/wave; hides under barrier+glue -------
    half8 b2r[KS2][4];
    #pragma unroll
    for (int ks = 0; ks < KS2; ++ks)
        #pragma unroll
        for (int f = 0; f < 4; ++f)
            b2r[ks][f] = *reinterpret_cast<const half8*>(
                b2f + ((ks * NB2 + wv * 4 + f) * 64 + lane) * 8);

    __syncthreads();

    // ================= glue: h, y1, Z = (y1 (x) h | y1 | 0) ==================
    if (tid < 64) {
        const int t = tid & 15, j = tid >> 4;
        float h[16];
        #pragma unroll
        for (int k = 0; k < 16; ++k) h[k] = fmaxf(c1s[t][k] + fc1b[k], 0.f);
        float y1 = c1s[t][80 + j];
        #pragma unroll
        for (int k = 0; k < 16; ++k) y1 = fmaf(c1s[t][16 + j * 16 + k], h[k], y1);
        y1 = fmaxf(y1, 0.f);
        #pragma unroll
        for (int k = 0; k < 16; k += 2) {
            half2_t p = pkrtz(y1 * h[k], y1 * h[k + 1]);
            *reinterpret_cast<half2_t*>(&zh[t][j * 16 + k]) = p;
        }
        zh[t][64 + j] = (_Float16)y1;
        #pragma unroll
        for (int p = 0; p < 7; ++p) zh[t][68 + j * 7 + p] = (_Float16)0.f;
    }
    __syncthreads();

    // ================= GEMM2: Z[16x96] * B2[96x512], B in regs ===============
    f32x4 acc2[4];
    #pragma unroll
    for (int f = 0; f < 4; ++f) acc2[f] = (f32x4){0.f, 0.f, 0.f, 0.f};

    #pragma unroll
    for (int ks = 0; ks < KS2; ++ks) {
        half8 az = *reinterpret_cast<const half8*>(&zh[rowA][ks * 32 + kgrp * 8]);
        #pragma unroll
        for (int f = 0; f < 4; ++f) acc2[f] = MFMA16(az, b2r[ks][f], acc2[f]);
    }

    // ================= relu + store ==========================================
    #pragma unroll
    for (int f = 0; f < 4; ++f) {
        const int e = (wv * 4 + f) * 16 + rowA;
        #pragma unroll
        for (int r = 0; r < 4; ++r) {
            out[(tok0 + kgrp * 4 + r) * EMBED + e] = fmaxf(acc2[f][r], 0.f);
        }
    }
}

extern "C" void kernel_launch(void* const* d_in, const int* in_sizes, int n_in,
                              void* d_out, int out_size, void* d_ws, size_t ws_size,
                              hipStream_t stream) {
    const float* x    = (const float*)d_in[0];
    const float* fc1w = (const float*)d_in[1];
    const float* fc1b = (const float*)d_in[2];
    const float* fc2w = (const float*)d_in[3];
    const float* fc2b = (const float*)d_in[4];
    float* out = (float*)d_out;

    _Float16* b1f = (_Float16*)d_ws;                   // 96 KB
    _Float16* b2f = b1f + B1ELEMS;                     // 96 KB

    prep<<<dim3((B1ELEMS + B2ELEMS) / 8 / 512), dim3(512), 0, stream>>>(fc1w, fc2w, fc2b, b1f, b2f);
    hyper_main<<<dim3(NTOK / MT), dim3(512), 0, stream>>>(x, fc1b, b1f, b2f, out);
}